// Round 5
// baseline (133.601 us; speedup 1.0000x reference)
//
#include <hip/hip_runtime.h>
#include <stdint.h>

#define M_DIM 8192
#define K_DIM 4096
#define N_DIM 4096
#define KB (K_DIM / 2)  // bytes per packed-fp4 row: 2048

typedef unsigned char u8;
typedef unsigned int u32;
typedef int i32x4 __attribute__((ext_vector_type(4)));
typedef int i32x8 __attribute__((ext_vector_type(8)));
typedef float f32x16 __attribute__((ext_vector_type(16)));
typedef float float4v __attribute__((ext_vector_type(4)));
typedef u32 u32x2 __attribute__((ext_vector_type(2)));

// sign(v) as fp4 e2m1 code: +1 -> 0x2, -1 -> 0xA, 0 -> 0x0
__device__ __forceinline__ u32 sign_fp4(float v) {
  return v > 0.0f ? 0x2u : (v < 0.0f ? 0xAu : 0x0u);
}

// -------- binarize X: [M][K] f32 -> [M][K/2] packed fp4 (k-major nibbles) ----
__global__ void binarize_x_kernel(const float* __restrict__ in, u32* __restrict__ out, int n8) {
  int i = blockIdx.x * blockDim.x + threadIdx.x;
  int stride = gridDim.x * blockDim.x;
  for (; i < n8; i += stride) {
    float4v v0 = ((const float4v*)in)[2 * i];
    float4v v1 = ((const float4v*)in)[2 * i + 1];
    u32 w = sign_fp4(v0.x) | (sign_fp4(v0.y) << 4) | (sign_fp4(v0.z) << 8) |
            (sign_fp4(v0.w) << 12) | (sign_fp4(v1.x) << 16) | (sign_fp4(v1.y) << 20) |
            (sign_fp4(v1.z) << 24) | (sign_fp4(v1.w) << 28);
    out[i] = w;
  }
}

// ---- binarize + transpose W: [K][N] f32 -> [N][K/2] packed fp4 -------------
__global__ void binT_w_kernel(const float* __restrict__ w, u8* __restrict__ wT) {
  __shared__ u8 tile[64][65];  // fp4 code per (n, k)
  const int bn = blockIdx.x * 64;
  const int bk = blockIdx.y * 64;
  const int tid = threadIdx.x;

#pragma unroll
  for (int it = 0; it < 4; ++it) {
    int idx = tid + it * 256;
    int r = idx >> 4;        // k-local
    int c = (idx & 15) * 4;  // n-local
    float4v v = *(const float4v*)&w[(size_t)(bk + r) * N_DIM + bn + c];
    tile[c + 0][r] = (u8)sign_fp4(v.x);
    tile[c + 1][r] = (u8)sign_fp4(v.y);
    tile[c + 2][r] = (u8)sign_fp4(v.z);
    tile[c + 3][r] = (u8)sign_fp4(v.w);
  }
  __syncthreads();
  // pack: each thread emits 8 bytes (16 k-codes) of one n-row
  const int rn = tid >> 2;       // n-local 0..63
  const int cb = (tid & 3) * 8;  // byte offset within the 32-B chunk
  u32x2 o;
  u32 lo = 0, hi = 0;
#pragma unroll
  for (int j = 0; j < 4; ++j) {
    lo |= (u32)(tile[rn][cb * 2 + 2 * j] | (tile[rn][cb * 2 + 2 * j + 1] << 4)) << (8 * j);
    hi |= (u32)(tile[rn][cb * 2 + 8 + 2 * j] | (tile[rn][cb * 2 + 9 + 2 * j] << 4)) << (8 * j);
  }
  o.x = lo;
  o.y = hi;
  *(u32x2*)&wT[(size_t)(bn + rn) * KB + (bk >> 1) + cb] = o;
}

// ------------------------------------------------------------------
// 8-phase 256x256 fp4 GEMM with 32x32x64 MFMA.
// C[M][N] = A[M][K] * Bt[N][K]^T, fp4 in, f32 out.
// K-tile = 256 elems = 128-B rows (byte-identical geometry to the validated
// i8/fp4 schedule). 8 waves (2M x 4N), double-buffered LDS, 4 phases/K-tile,
// T2 byte-XOR swizzle via pre-swizzled global source, counted vmcnt(4).
// ------------------------------------------------------------------
#define BM 256
#define BN 256
#define BKB 128           // bytes of K per tile (= 256 fp4 elems)
#define NT (K_DIM / 256)  // 16

__device__ __forceinline__ void gload_lds16(const u8* g, u8* l) {
  __builtin_amdgcn_global_load_lds(
      (const __attribute__((address_space(1))) void*)g,
      (__attribute__((address_space(3))) void*)l, 16, 0, 0);
}

__device__ __forceinline__ i32x8 pad8(i32x4 v) {
  return __builtin_shufflevector(v, v, 0, 1, 2, 3, 0, 1, 2, 3);
}

// fp4 x fp4 32x32x64, per-lane e8m0 scale byte 0x7F (=1.0), opsel 0
__device__ __forceinline__ f32x16 mfma_fp4_32(i32x8 a, i32x8 b, f32x16 c) {
  return __builtin_amdgcn_mfma_scale_f32_32x32x64_f8f6f4(a, b, c, 4, 4, 0, 0x7F, 0, 0x7F);
}

__global__ __launch_bounds__(512, 2) void gemm_bin_fp4(const u8* __restrict__ A,
                                                       const u8* __restrict__ Bt,
                                                       float* __restrict__ C) {
  // slots: 0 = A rows[0,128), 1 = A rows[128,256), 2 = Bt[0,128), 3 = Bt[128,256)
  // each slot 128 rows x 128 B = 16 KiB; 2 bufs x 4 slots = 128 KiB.
  __shared__ u8 lds[2][4][128 * 128];

  const int tid = threadIdx.x;
  const int lane = tid & 63;
  const int wid = tid >> 6;  // 0..7
  const int wr = wid >> 2;   // 0..1 (M half)
  const int wc = wid & 3;    // 0..3 (N quarter)

  // XCD-aware swizzle, nwg = 512 (divisible by 8 -> bijective)
  const int b = blockIdx.x;
  const int sw = (b & 7) * (gridDim.x >> 3) + (b >> 3);
  const int tiles_n = N_DIM / BN;  // 16
  const int bm = (sw / tiles_n) * BM;
  const int bn = (sw % tiles_n) * BN;

  const int l31 = lane & 31;
  const int g5 = lane >> 5;
  const int srow = lane >> 3;                      // 0..7
  const int swz_src = (((lane & 7) ^ srow) << 4);  // pre-swizzled byte col

  // stage one 128-row x 128-B half-tile (2 x global_load_lds per wave).
  auto stage = [&](int buf, int slot, const u8* gbase) {
#pragma unroll
    for (int i = 0; i < 2; ++i) {
      const u8* g = gbase + (size_t)(i * 64 + wid * 8 + srow) * KB + swz_src;
      gload_lds16(g, &lds[buf][slot][(i * 64 + wid * 8) * 128]);
    }
  };

  f32x16 acc[4][2] = {};

  // ---- prologue: tile0 fully + B-halves of tile1 (6 half-tiles, 12 loads) ----
  {
    const u8* Abase = A + (size_t)bm * KB;
    const u8* Bbase = Bt + (size_t)bn * KB;
    stage(0, 0, Abase);
    stage(0, 1, Abase + (size_t)128 * KB);
    stage(0, 2, Bbase);
    stage(0, 3, Bbase + (size_t)128 * KB);
    stage(1, 2, Bbase + BKB);
    stage(1, 3, Bbase + (size_t)128 * KB + BKB);
  }
  asm volatile("s_waitcnt vmcnt(4)" ::: "memory");  // tile0 ready, B(1) in flight
  __builtin_amdgcn_s_barrier();

  i32x4 a[2][4], b0[4], b1[4];

  for (int t = 0; t < NT; ++t) {
    const int buf = t & 1;
    const u8* As = &lds[buf][wr][0];
    const u8* Bs = &lds[buf][2 + (wc >> 1)][0];
    const int brow0 = (wc & 1) * 64;
    const u8* Anext = A + (size_t)bm * KB + (t + 1) * BKB;    // tile t+1
    const u8* Bnext2 = Bt + (size_t)bn * KB + (t + 2) * BKB;  // tile t+2

    // ===== phase 1: read a(m01)+b0 ; stage A0(t+1) ; MFMA (m01 x n0) =====
#pragma unroll
    for (int m = 0; m < 2; ++m)
#pragma unroll
      for (int ks = 0; ks < 4; ++ks) {
        int row = m * 32 + l31;
        int col = (ks * 32 + g5 * 16) ^ ((row & 7) << 4);
        a[m][ks] = *(const i32x4*)&As[row * 128 + col];
      }
#pragma unroll
    for (int ks = 0; ks < 4; ++ks) {
      int row = brow0 + l31;
      int col = (ks * 32 + g5 * 16) ^ ((row & 7) << 4);
      b0[ks] = *(const i32x4*)&Bs[row * 128 + col];
    }
    if (t + 1 < NT) stage(buf ^ 1, 0, Anext);
    __builtin_amdgcn_s_barrier();
    asm volatile("s_waitcnt lgkmcnt(0)" ::: "memory");
    __builtin_amdgcn_sched_barrier(0);
    __builtin_amdgcn_s_setprio(1);
    {
      i32x8 pb[4];
#pragma unroll
      for (int ks = 0; ks < 4; ++ks) pb[ks] = pad8(b0[ks]);
#pragma unroll
      for (int ks = 0; ks < 4; ++ks)
#pragma unroll
        for (int m = 0; m < 2; ++m)
          acc[m][0] = mfma_fp4_32(pad8(a[m][ks]), pb[ks], acc[m][0]);
    }
    __builtin_amdgcn_s_setprio(0);
    __builtin_amdgcn_s_barrier();

    // ===== phase 2: read b1 ; stage A1(t+1) ; MFMA (m01 x n1) =====
#pragma unroll
    for (int ks = 0; ks < 4; ++ks) {
      int row = brow0 + 32 + l31;
      int col = (ks * 32 + g5 * 16) ^ ((row & 7) << 4);
      b1[ks] = *(const i32x4*)&Bs[row * 128 + col];
    }
    if (t + 1 < NT) stage(buf ^ 1, 1, Anext + (size_t)128 * KB);
    __builtin_amdgcn_s_barrier();
    asm volatile("s_waitcnt lgkmcnt(0)" ::: "memory");
    __builtin_amdgcn_sched_barrier(0);
    __builtin_amdgcn_s_setprio(1);
    {
      i32x8 pb[4];
#pragma unroll
      for (int ks = 0; ks < 4; ++ks) pb[ks] = pad8(b1[ks]);
#pragma unroll
      for (int ks = 0; ks < 4; ++ks)
#pragma unroll
        for (int m = 0; m < 2; ++m)
          acc[m][1] = mfma_fp4_32(pad8(a[m][ks]), pb[ks], acc[m][1]);
    }
    __builtin_amdgcn_s_setprio(0);
    __builtin_amdgcn_s_barrier();

    // ===== phase 3: read a(m23) ; stage B0(t+2) ; MFMA (m23 x n0) =====
#pragma unroll
    for (int m = 0; m < 2; ++m)
#pragma unroll
      for (int ks = 0; ks < 4; ++ks) {
        int row = 64 + m * 32 + l31;
        int col = (ks * 32 + g5 * 16) ^ ((row & 7) << 4);
        a[m][ks] = *(const i32x4*)&As[row * 128 + col];
      }
    if (t + 2 < NT) stage(buf, 2, Bnext2);
    __builtin_amdgcn_s_barrier();
    asm volatile("s_waitcnt lgkmcnt(0)" ::: "memory");
    __builtin_amdgcn_sched_barrier(0);
    __builtin_amdgcn_s_setprio(1);
    {
      i32x8 pb[4];
#pragma unroll
      for (int ks = 0; ks < 4; ++ks) pb[ks] = pad8(b0[ks]);
#pragma unroll
      for (int ks = 0; ks < 4; ++ks)
#pragma unroll
        for (int m = 0; m < 2; ++m)
          acc[2 + m][0] = mfma_fp4_32(pad8(a[m][ks]), pb[ks], acc[2 + m][0]);
    }
    __builtin_amdgcn_s_setprio(0);
    __builtin_amdgcn_s_barrier();

    // ===== phase 4: stage B1(t+2) ; MFMA (m23 x n1) ; counted vmcnt =====
    if (t + 2 < NT) stage(buf, 3, Bnext2 + (size_t)128 * KB);
    __builtin_amdgcn_s_barrier();
    __builtin_amdgcn_s_setprio(1);
    {
      i32x8 pb[4];
#pragma unroll
      for (int ks = 0; ks < 4; ++ks) pb[ks] = pad8(b1[ks]);
#pragma unroll
      for (int ks = 0; ks < 4; ++ks)
#pragma unroll
        for (int m = 0; m < 2; ++m)
          acc[2 + m][1] = mfma_fp4_32(pad8(a[m][ks]), pb[ks], acc[2 + m][1]);
    }
    __builtin_amdgcn_s_setprio(0);
    // drain tile t+1's half-tiles; keep B(t+2) (4 loads) in flight
    if (t + 2 < NT)
      asm volatile("s_waitcnt vmcnt(4)" ::: "memory");
    else
      asm volatile("s_waitcnt vmcnt(0)" ::: "memory");
    __builtin_amdgcn_s_barrier();
  }

  // ---- epilogue: 32x32 C/D layout col = lane&31, row = (reg&3)+8*(reg>>2)+4*(lane>>5) ----
  const int crow0 = bm + wr * 128;
  const int ccol0 = bn + wc * 64;
#pragma unroll
  for (int mt = 0; mt < 4; ++mt)
#pragma unroll
    for (int nt = 0; nt < 2; ++nt)
#pragma unroll
      for (int j = 0; j < 16; ++j) {
        int row = crow0 + mt * 32 + (j & 3) + 8 * (j >> 2) + 4 * g5;
        C[(size_t)row * N_DIM + ccol0 + nt * 32 + l31] = acc[mt][nt][j];
      }
}

// -------- naive fallback (only if workspace is too small) --------
__global__ void naive_bin_gemm(const float* __restrict__ X, const float* __restrict__ W,
                               float* __restrict__ C) {
  int j = blockIdx.x * blockDim.x + threadIdx.x;
  int i = blockIdx.y;
  if (j >= N_DIM) return;
  float s = 0.0f;
  for (int k = 0; k < K_DIM; ++k) {
    float xv = X[(size_t)i * K_DIM + k];
    float wv = W[(size_t)k * N_DIM + j];
    float sx = (float)((xv > 0.0f) - (xv < 0.0f));
    float sw = (float)((wv > 0.0f) - (wv < 0.0f));
    s += sx * sw;
  }
  C[(size_t)i * N_DIM + j] = s;
}

extern "C" void kernel_launch(void* const* d_in, const int* in_sizes, int n_in,
                              void* d_out, int out_size, void* d_ws, size_t ws_size,
                              hipStream_t stream) {
  const float* x = (const float*)d_in[0];  // [M][K]
  const float* w = (const float*)d_in[1];  // [K][N]
  float* out = (float*)d_out;              // [M][N]

  const size_t xb_bytes = (size_t)M_DIM * KB;  // 16.8 MB
  const size_t wt_bytes = (size_t)N_DIM * KB;  // 8.4 MB

  if (ws_size >= xb_bytes + wt_bytes) {
    u8* xb = (u8*)d_ws;
    u8* wt = (u8*)((char*)d_ws + xb_bytes);

    binarize_x_kernel<<<2048, 256, 0, stream>>>(x, (u32*)xb, M_DIM * K_DIM / 8);
    binT_w_kernel<<<dim3(N_DIM / 64, K_DIM / 64), dim3(256), 0, stream>>>(w, wt);

    const int grid = (M_DIM / BM) * (N_DIM / BN);  // 32 * 16 = 512
    gemm_bin_fp4<<<grid, 512, 0, stream>>>(xb, wt, out);
  } else {
    naive_bin_gemm<<<dim3(N_DIM / 256, M_DIM), dim3(256), 0, stream>>>(x, w, out);
  }
}

// Round 6
// 127.861 us; speedup vs baseline: 1.0449x; 1.0449x over previous
//
#include <hip/hip_runtime.h>
#include <stdint.h>

#define M_DIM 8192
#define K_DIM 4096
#define N_DIM 4096
#define KB (K_DIM / 2)  // bytes per packed-fp4 row: 2048

typedef unsigned char u8;
typedef unsigned int u32;
typedef int i32x4 __attribute__((ext_vector_type(4)));
typedef int i32x8 __attribute__((ext_vector_type(8)));
typedef float f32x4 __attribute__((ext_vector_type(4)));
typedef float float4v __attribute__((ext_vector_type(4)));
typedef u32 u32x2 __attribute__((ext_vector_type(2)));

// sign(v) as fp4 e2m1 code: +1 -> 0x2, -1 -> 0xA, 0 -> 0x0
__device__ __forceinline__ u32 sign_fp4(float v) {
  return v > 0.0f ? 0x2u : (v < 0.0f ? 0xAu : 0x0u);
}

// ---------------- fused preprocessing -----------------------------
// blocks [0, 4096):       binarize+transpose W: [K][N] f32 -> [N][K/2] fp4
// blocks [4096, 6144):    binarize X: [M][K] f32 -> [M][K/2] fp4 (grid-stride)
// Independent streams of work in ONE launch so they share the GPU.
__global__ void binarize_fused(const float* __restrict__ x, const float* __restrict__ w,
                               u32* __restrict__ xb, u8* __restrict__ wT) {
  const int tid = threadIdx.x;
  if (blockIdx.x < 4096) {
    // ---- W transpose part: one 64x64 tile per block ----
    __shared__ u8 tile[64][65];  // fp4 code per (n, k)
    const int bid = blockIdx.x;
    const int bn = (bid & 63) * 64;
    const int bk = (bid >> 6) * 64;

#pragma unroll
    for (int it = 0; it < 4; ++it) {
      int idx = tid + it * 256;
      int r = idx >> 4;        // k-local
      int c = (idx & 15) * 4;  // n-local
      float4v v = *(const float4v*)&w[(size_t)(bk + r) * N_DIM + bn + c];
      tile[c + 0][r] = (u8)sign_fp4(v.x);
      tile[c + 1][r] = (u8)sign_fp4(v.y);
      tile[c + 2][r] = (u8)sign_fp4(v.z);
      tile[c + 3][r] = (u8)sign_fp4(v.w);
    }
    __syncthreads();
    // pack: each thread emits 8 bytes (16 k-codes) of one n-row
    const int rn = tid >> 2;       // n-local 0..63
    const int cb = (tid & 3) * 8;  // byte offset within the 32-B chunk
    u32x2 o;
    u32 lo = 0, hi = 0;
#pragma unroll
    for (int j = 0; j < 4; ++j) {
      lo |= (u32)(tile[rn][cb * 2 + 2 * j] | (tile[rn][cb * 2 + 2 * j + 1] << 4)) << (8 * j);
      hi |= (u32)(tile[rn][cb * 2 + 8 + 2 * j] | (tile[rn][cb * 2 + 9 + 2 * j] << 4)) << (8 * j);
    }
    o.x = lo;
    o.y = hi;
    *(u32x2*)&wT[(size_t)(bn + rn) * KB + (bk >> 1) + cb] = o;
  } else {
    // ---- X binarize part ----
    const int n8 = M_DIM * K_DIM / 8;
    int i = (blockIdx.x - 4096) * 256 + tid;
    const int stride = 2048 * 256;
    for (; i < n8; i += stride) {
      float4v v0 = ((const float4v*)x)[2 * i];
      float4v v1 = ((const float4v*)x)[2 * i + 1];
      u32 wd = sign_fp4(v0.x) | (sign_fp4(v0.y) << 4) | (sign_fp4(v0.z) << 8) |
               (sign_fp4(v0.w) << 12) | (sign_fp4(v1.x) << 16) | (sign_fp4(v1.y) << 20) |
               (sign_fp4(v1.z) << 24) | (sign_fp4(v1.w) << 28);
      xb[i] = wd;
    }
  }
}

// ------------------------------------------------------------------
// 8-phase 256x256 fp4 GEMM: C[M][N] = A[M][K] * Bt[N][K]^T, fp4 in, f32 out.
// mfma_scale_f32_16x16x128_f8f6f4 (fp4/fp4, scale=1.0). K-tile = 256 elems =
// 128 B rows. 8 waves (2M x 4N), double-buffered LDS, 4 phases/K-tile,
// T2 byte-XOR swizzle via pre-swizzled global source, counted vmcnt(4),
// setprio. pad8 uses UNDEF hi half (fp4 reads only regs [0:3]) so regalloc
// coalesces the copy instead of emitting 8 v_movs per operand.
// ------------------------------------------------------------------
#define BM 256
#define BN 256
#define BKB 128           // bytes of K per tile (= 256 fp4 elems)
#define NT (K_DIM / 256)  // 16

__device__ __forceinline__ void gload_lds16(const u8* g, u8* l) {
  __builtin_amdgcn_global_load_lds(
      (const __attribute__((address_space(1))) void*)g,
      (__attribute__((address_space(3))) void*)l, 16, 0, 0);
}

// undef hi half: fp4 f8f6f4 MFMA ignores regs [4:7] of each operand
__device__ __forceinline__ i32x8 pad8(i32x4 v) {
  return __builtin_shufflevector(v, v, 0, 1, 2, 3, -1, -1, -1, -1);
}

// fp4 x fp4, per-lane e8m0 scale byte 0x7F (=1.0), opsel byte 0
__device__ __forceinline__ f32x4 mfma_fp4(i32x4 a, i32x4 b, f32x4 c) {
  return __builtin_amdgcn_mfma_scale_f32_16x16x128_f8f6f4(pad8(a), pad8(b), c, 4, 4, 0, 0x7F, 0,
                                                          0x7F);
}

__global__ __launch_bounds__(512, 2) void gemm_bin_fp4(const u8* __restrict__ A,
                                                       const u8* __restrict__ Bt,
                                                       float* __restrict__ C) {
  // slots: 0 = A rows[0,128), 1 = A rows[128,256), 2 = Bt[0,128), 3 = Bt[128,256)
  // each slot 128 rows x 128 B = 16 KiB; 2 bufs x 4 slots = 128 KiB.
  __shared__ u8 lds[2][4][128 * 128];

  const int tid = threadIdx.x;
  const int lane = tid & 63;
  const int wid = tid >> 6;  // 0..7
  const int wr = wid >> 2;   // 0..1 (M half)
  const int wc = wid & 3;    // 0..3 (N quarter)

  // XCD-aware swizzle, nwg = 512 (divisible by 8 -> bijective)
  const int b = blockIdx.x;
  const int sw = (b & 7) * (gridDim.x >> 3) + (b >> 3);
  const int tiles_n = N_DIM / BN;  // 16
  const int bm = (sw / tiles_n) * BM;
  const int bn = (sw % tiles_n) * BN;

  const int l15 = lane & 15;
  const int g4 = lane >> 4;
  const int srow = lane >> 3;                      // 0..7
  const int swz_src = (((lane & 7) ^ srow) << 4);  // pre-swizzled byte col

  // stage one 128-row x 128-B half-tile (2 x global_load_lds per wave).
  auto stage = [&](int buf, int slot, const u8* gbase) {
#pragma unroll
    for (int i = 0; i < 2; ++i) {
      const u8* g = gbase + (size_t)(i * 64 + wid * 8 + srow) * KB + swz_src;
      gload_lds16(g, &lds[buf][slot][(i * 64 + wid * 8) * 128]);
    }
  };

  f32x4 acc[8][4] = {};

  // ---- prologue: tile0 fully + B-halves of tile1 (6 half-tiles, 12 loads) ----
  {
    const u8* Abase = A + (size_t)bm * KB;
    const u8* Bbase = Bt + (size_t)bn * KB;
    stage(0, 0, Abase);
    stage(0, 1, Abase + (size_t)128 * KB);
    stage(0, 2, Bbase);
    stage(0, 3, Bbase + (size_t)128 * KB);
    stage(1, 2, Bbase + BKB);
    stage(1, 3, Bbase + (size_t)128 * KB + BKB);
  }
  asm volatile("s_waitcnt vmcnt(4)" ::: "memory");  // tile0 ready, B(1) in flight
  __builtin_amdgcn_s_barrier();

  i32x4 a[4][2], b01[2][2], b23[2][2];

  for (int t = 0; t < NT; ++t) {
    const int buf = t & 1;
    const u8* As = &lds[buf][wr][0];
    const u8* Bs = &lds[buf][2 + (wc >> 1)][0];
    const int brow0 = (wc & 1) * 64;
    const u8* Anext = A + (size_t)bm * KB + (t + 1) * BKB;    // tile t+1
    const u8* Bnext2 = Bt + (size_t)bn * KB + (t + 2) * BKB;  // tile t+2

    // ===== phase 1: read a(mh0) + b01 ; stage A0(t+1) ; MFMA Q(mh0,n01) =====
#pragma unroll
    for (int m = 0; m < 4; ++m)
#pragma unroll
      for (int kk = 0; kk < 2; ++kk) {
        int row = m * 16 + l15;
        int col = (kk * 64 + g4 * 16) ^ ((row & 7) << 4);
        a[m][kk] = *(const i32x4*)&As[row * 128 + col];
      }
#pragma unroll
    for (int n = 0; n < 2; ++n)
#pragma unroll
      for (int kk = 0; kk < 2; ++kk) {
        int row = brow0 + n * 16 + l15;
        int col = (kk * 64 + g4 * 16) ^ ((row & 7) << 4);
        b01[n][kk] = *(const i32x4*)&Bs[row * 128 + col];
      }
    if (t + 1 < NT) stage(buf ^ 1, 0, Anext);
    __builtin_amdgcn_s_barrier();
    asm volatile("s_waitcnt lgkmcnt(0)" ::: "memory");
    __builtin_amdgcn_sched_barrier(0);
    __builtin_amdgcn_s_setprio(1);
#pragma unroll
    for (int kk = 0; kk < 2; ++kk)
#pragma unroll
      for (int m = 0; m < 4; ++m)
#pragma unroll
        for (int n = 0; n < 2; ++n)
          acc[m][n] = mfma_fp4(a[m][kk], b01[n][kk], acc[m][n]);
    __builtin_amdgcn_s_setprio(0);
    __builtin_amdgcn_s_barrier();

    // ===== phase 2: read b23 ; stage A1(t+1) ; MFMA Q(mh0,n23) =====
#pragma unroll
    for (int n = 0; n < 2; ++n)
#pragma unroll
      for (int kk = 0; kk < 2; ++kk) {
        int row = brow0 + (2 + n) * 16 + l15;
        int col = (kk * 64 + g4 * 16) ^ ((row & 7) << 4);
        b23[n][kk] = *(const i32x4*)&Bs[row * 128 + col];
      }
    if (t + 1 < NT) stage(buf ^ 1, 1, Anext + (size_t)128 * KB);
    __builtin_amdgcn_s_barrier();
    asm volatile("s_waitcnt lgkmcnt(0)" ::: "memory");
    __builtin_amdgcn_sched_barrier(0);
    __builtin_amdgcn_s_setprio(1);
#pragma unroll
    for (int kk = 0; kk < 2; ++kk)
#pragma unroll
      for (int m = 0; m < 4; ++m)
#pragma unroll
        for (int n = 0; n < 2; ++n)
          acc[m][2 + n] = mfma_fp4(a[m][kk], b23[n][kk], acc[m][2 + n]);
    __builtin_amdgcn_s_setprio(0);
    __builtin_amdgcn_s_barrier();

    // ===== phase 3: read a(mh1) ; stage B0(t+2) ; MFMA Q(mh1,n01) =====
#pragma unroll
    for (int m = 0; m < 4; ++m)
#pragma unroll
      for (int kk = 0; kk < 2; ++kk) {
        int row = 64 + m * 16 + l15;
        int col = (kk * 64 + g4 * 16) ^ ((row & 7) << 4);
        a[m][kk] = *(const i32x4*)&As[row * 128 + col];
      }
    if (t + 2 < NT) stage(buf, 2, Bnext2);
    __builtin_amdgcn_s_barrier();
    asm volatile("s_waitcnt lgkmcnt(0)" ::: "memory");
    __builtin_amdgcn_sched_barrier(0);
    __builtin_amdgcn_s_setprio(1);
#pragma unroll
    for (int kk = 0; kk < 2; ++kk)
#pragma unroll
      for (int m = 0; m < 4; ++m)
#pragma unroll
        for (int n = 0; n < 2; ++n)
          acc[4 + m][n] = mfma_fp4(a[m][kk], b01[n][kk], acc[4 + m][n]);
    __builtin_amdgcn_s_setprio(0);
    __builtin_amdgcn_s_barrier();

    // ===== phase 4: stage B1(t+2) ; MFMA Q(mh1,n23) ; counted vmcnt =====
    if (t + 2 < NT) stage(buf, 3, Bnext2 + (size_t)128 * KB);
    __builtin_amdgcn_s_barrier();
    __builtin_amdgcn_s_setprio(1);
#pragma unroll
    for (int kk = 0; kk < 2; ++kk)
#pragma unroll
      for (int m = 0; m < 4; ++m)
#pragma unroll
        for (int n = 0; n < 2; ++n)
          acc[4 + m][2 + n] = mfma_fp4(a[m][kk], b23[n][kk], acc[4 + m][2 + n]);
    __builtin_amdgcn_s_setprio(0);
    // drain tile t+1's half-tiles; keep B(t+2) (4 loads) in flight
    if (t + 2 < NT)
      asm volatile("s_waitcnt vmcnt(4)" ::: "memory");
    else
      asm volatile("s_waitcnt vmcnt(0)" ::: "memory");
    __builtin_amdgcn_s_barrier();
  }

  // ---- epilogue: C/D layout col = lane&15, row = (lane>>4)*4 + reg ----
  const int crow0 = bm + wr * 128;
  const int ccol0 = bn + wc * 64;
#pragma unroll
  for (int m = 0; m < 8; ++m)
#pragma unroll
    for (int n = 0; n < 4; ++n)
#pragma unroll
      for (int j = 0; j < 4; ++j)
        C[(size_t)(crow0 + m * 16 + g4 * 4 + j) * N_DIM + ccol0 + n * 16 + l15] = acc[m][n][j];
}

// -------- naive fallback (only if workspace is too small) --------
__global__ void naive_bin_gemm(const float* __restrict__ X, const float* __restrict__ W,
                               float* __restrict__ C) {
  int j = blockIdx.x * blockDim.x + threadIdx.x;
  int i = blockIdx.y;
  if (j >= N_DIM) return;
  float s = 0.0f;
  for (int k = 0; k < K_DIM; ++k) {
    float xv = X[(size_t)i * K_DIM + k];
    float wv = W[(size_t)k * N_DIM + j];
    float sx = (float)((xv > 0.0f) - (xv < 0.0f));
    float sw = (float)((wv > 0.0f) - (wv < 0.0f));
    s += sx * sw;
  }
  C[(size_t)i * N_DIM + j] = s;
}

extern "C" void kernel_launch(void* const* d_in, const int* in_sizes, int n_in,
                              void* d_out, int out_size, void* d_ws, size_t ws_size,
                              hipStream_t stream) {
  const float* x = (const float*)d_in[0];  // [M][K]
  const float* w = (const float*)d_in[1];  // [K][N]
  float* out = (float*)d_out;              // [M][N]

  const size_t xb_bytes = (size_t)M_DIM * KB;  // 16.8 MB
  const size_t wt_bytes = (size_t)N_DIM * KB;  // 8.4 MB

  if (ws_size >= xb_bytes + wt_bytes) {
    u8* xb = (u8*)d_ws;
    u8* wt = (u8*)((char*)d_ws + xb_bytes);

    binarize_fused<<<4096 + 2048, 256, 0, stream>>>(x, w, (u32*)xb, wt);

    const int grid = (M_DIM / BM) * (N_DIM / BN);  // 32 * 16 = 512
    gemm_bin_fp4<<<grid, 512, 0, stream>>>(xb, wt, out);
  } else {
    naive_bin_gemm<<<dim3(N_DIM / 256, M_DIM), dim3(256), 0, stream>>>(x, w, out);
  }
}

// Round 7
// 127.381 us; speedup vs baseline: 1.0488x; 1.0038x over previous
//
#include <hip/hip_runtime.h>
#include <stdint.h>

#define M_DIM 8192
#define K_DIM 4096
#define N_DIM 4096
#define KB (K_DIM / 2)  // bytes per packed-fp4 row: 2048

typedef unsigned char u8;
typedef unsigned int u32;
typedef int i32x4 __attribute__((ext_vector_type(4)));
typedef int i32x8 __attribute__((ext_vector_type(8)));
typedef float f32x4 __attribute__((ext_vector_type(4)));
typedef float float4v __attribute__((ext_vector_type(4)));
typedef u32 u32x2 __attribute__((ext_vector_type(2)));

// sign(v) as fp4 e2m1 code: +1 -> 0x2, -1 -> 0xA, 0 -> 0x0
__device__ __forceinline__ u32 sign_fp4(float v) {
  return v > 0.0f ? 0x2u : (v < 0.0f ? 0xAu : 0x0u);
}

// pack 4 byte-codes (one per byte of v) into 4 nibbles (16-bit result)
__device__ __forceinline__ u32 pk16(u32 v) {
  return (v & 0xFu) | ((v >> 4) & 0xF0u) | ((v >> 8) & 0xF00u) | ((v >> 12) & 0xF000u);
}

// ---------------- fused preprocessing -----------------------------
// blocks [0, 4096):       binarize+transpose W: [K][N] f32 -> [N][K/2] fp4
// blocks [4096, 6144):    binarize X: [M][K] f32 -> [M][K/2] fp4 (grid-stride)
__global__ void binarize_fused(const float* __restrict__ x, const float* __restrict__ w,
                               u32* __restrict__ xb, u8* __restrict__ wT) {
  const int tid = threadIdx.x;
  if (blockIdx.x < 4096) {
    // ---- W transpose part: one 64x64 tile per block ----
    __shared__ u8 tile[64][68];  // 68-B rows: 4-aligned, odd dword stride
    const int bid = blockIdx.x;
    const int bn = (bid & 63) * 64;
    const int bk = (bid >> 6) * 64;

#pragma unroll
    for (int it = 0; it < 4; ++it) {
      int idx = tid + it * 256;
      int r = idx >> 4;        // k-local
      int c = (idx & 15) * 4;  // n-local
      float4v v = *(const float4v*)&w[(size_t)(bk + r) * N_DIM + bn + c];
      tile[c + 0][r] = (u8)sign_fp4(v.x);
      tile[c + 1][r] = (u8)sign_fp4(v.y);
      tile[c + 2][r] = (u8)sign_fp4(v.z);
      tile[c + 3][r] = (u8)sign_fp4(v.w);
    }
    __syncthreads();
    // pack: each thread emits 8 output bytes (16 k-codes) of one n-row,
    // reading 16 code-bytes as 4 aligned u32s.
    const int rn = tid >> 2;          // n-local 0..63
    const int cbyte = (tid & 3) * 8;  // output byte offset 0..24
    const u32* trow = (const u32*)&tile[rn][0];
    u32 q0 = trow[cbyte / 2 + 0];
    u32 q1 = trow[cbyte / 2 + 1];
    u32 q2 = trow[cbyte / 2 + 2];
    u32 q3 = trow[cbyte / 2 + 3];
    u32x2 o;
    o.x = pk16(q0) | (pk16(q1) << 16);
    o.y = pk16(q2) | (pk16(q3) << 16);
    *(u32x2*)&wT[(size_t)(bn + rn) * KB + (bk >> 1) + cbyte] = o;
  } else {
    // ---- X binarize part ----
    const int n8 = M_DIM * K_DIM / 8;
    int i = (blockIdx.x - 4096) * 256 + tid;
    const int stride = 2048 * 256;
    for (; i < n8; i += stride) {
      float4v v0 = ((const float4v*)x)[2 * i];
      float4v v1 = ((const float4v*)x)[2 * i + 1];
      u32 wd = sign_fp4(v0.x) | (sign_fp4(v0.y) << 4) | (sign_fp4(v0.z) << 8) |
               (sign_fp4(v0.w) << 12) | (sign_fp4(v1.x) << 16) | (sign_fp4(v1.y) << 20) |
               (sign_fp4(v1.z) << 24) | (sign_fp4(v1.w) << 28);
      xb[i] = wd;
    }
  }
}

// ------------------------------------------------------------------
// 8-phase 256x256 fp4 GEMM: C[M][N] = A[M][K] * Bt[N][K]^T, fp4 in, f32 out.
// mfma_scale_f32_16x16x128_f8f6f4 (fp4/fp4, scale=1.0). K-tile = 256 elems =
// 128-B rows. 8 waves (2M x 4N), double-buffered LDS, 4 phases/K-tile split
// along kk (ds_reads balanced 8/8/4/4), T2 byte-XOR swizzle via pre-swizzled
// global source, counted vmcnt(4), setprio around MFMA clusters.
// ------------------------------------------------------------------
#define BM 256
#define BN 256
#define BKB 128           // bytes of K per tile (= 256 fp4 elems)
#define NT (K_DIM / 256)  // 16

__device__ __forceinline__ void gload_lds16(const u8* g, u8* l) {
  __builtin_amdgcn_global_load_lds(
      (const __attribute__((address_space(1))) void*)g,
      (__attribute__((address_space(3))) void*)l, 16, 0, 0);
}

// undef hi half: fp4 f8f6f4 MFMA ignores regs [4:7] of each operand
__device__ __forceinline__ i32x8 pad8(i32x4 v) {
  return __builtin_shufflevector(v, v, 0, 1, 2, 3, -1, -1, -1, -1);
}

// fp4 x fp4, per-lane e8m0 scale byte 0x7F (=1.0), opsel byte 0
__device__ __forceinline__ f32x4 mfma_fp4(i32x4 a, i32x4 b, f32x4 c) {
  return __builtin_amdgcn_mfma_scale_f32_16x16x128_f8f6f4(pad8(a), pad8(b), c, 4, 4, 0, 0x7F, 0,
                                                          0x7F);
}

__global__ __launch_bounds__(512, 2) void gemm_bin_fp4(const u8* __restrict__ A,
                                                       const u8* __restrict__ Bt,
                                                       float* __restrict__ C) {
  // slots: 0 = A rows[0,128), 1 = A rows[128,256), 2 = Bt[0,128), 3 = Bt[128,256)
  // each slot 128 rows x 128 B = 16 KiB; 2 bufs x 4 slots = 128 KiB.
  __shared__ u8 lds[2][4][128 * 128];

  const int tid = threadIdx.x;
  const int lane = tid & 63;
  const int wid = tid >> 6;  // 0..7
  const int wr = wid >> 2;   // 0..1 (M half)
  const int wc = wid & 3;    // 0..3 (N quarter)

  // XCD-aware swizzle, nwg = 512 (divisible by 8 -> bijective)
  const int b = blockIdx.x;
  const int sw = (b & 7) * (gridDim.x >> 3) + (b >> 3);
  const int tiles_n = N_DIM / BN;  // 16
  const int bm = (sw / tiles_n) * BM;
  const int bn = (sw % tiles_n) * BN;

  const int l15 = lane & 15;
  const int g4 = lane >> 4;
  const int srow = lane >> 3;                      // 0..7
  const int swz_src = (((lane & 7) ^ srow) << 4);  // pre-swizzled byte col

  // stage one 128-row x 128-B half-tile (2 x global_load_lds per wave).
  auto stage = [&](int buf, int slot, const u8* gbase) {
#pragma unroll
    for (int i = 0; i < 2; ++i) {
      const u8* g = gbase + (size_t)(i * 64 + wid * 8 + srow) * KB + swz_src;
      gload_lds16(g, &lds[buf][slot][(i * 64 + wid * 8) * 128]);
    }
  };

  f32x4 acc[8][4] = {};

  // ---- prologue: tile0 fully + B-halves of tile1 (6 half-tiles, 12 loads) ----
  {
    const u8* Abase = A + (size_t)bm * KB;
    const u8* Bbase = Bt + (size_t)bn * KB;
    stage(0, 0, Abase);
    stage(0, 1, Abase + (size_t)128 * KB);
    stage(0, 2, Bbase);
    stage(0, 3, Bbase + (size_t)128 * KB);
    stage(1, 2, Bbase + BKB);
    stage(1, 3, Bbase + (size_t)128 * KB + BKB);
  }
  asm volatile("s_waitcnt vmcnt(4)" ::: "memory");  // tile0 ready, B(1) in flight
  __builtin_amdgcn_s_barrier();

  i32x4 av[4], b0[4], b1[4];

  for (int t = 0; t < NT; ++t) {
    const int buf = t & 1;
    const u8* As = &lds[buf][wr][0];
    const u8* Bs = &lds[buf][2 + (wc >> 1)][0];
    const int brow0 = (wc & 1) * 64;
    const u8* Anext = A + (size_t)bm * KB + (t + 1) * BKB;    // tile t+1
    const u8* Bnext2 = Bt + (size_t)bn * KB + (t + 2) * BKB;  // tile t+2

    // ===== phase 1: read A(mh0,k0)+B(*,k0) ; stage A0(t+1) ; MFMA mh0 x k0 =====
#pragma unroll
    for (int m = 0; m < 4; ++m) {
      int row = m * 16 + l15;
      int col = (g4 * 16) ^ ((row & 7) << 4);
      av[m] = *(const i32x4*)&As[row * 128 + col];
    }
#pragma unroll
    for (int n = 0; n < 4; ++n) {
      int row = brow0 + n * 16 + l15;
      int col = (g4 * 16) ^ ((row & 7) << 4);
      b0[n] = *(const i32x4*)&Bs[row * 128 + col];
    }
    if (t + 1 < NT) stage(buf ^ 1, 0, Anext);
    __builtin_amdgcn_s_barrier();
    asm volatile("s_waitcnt lgkmcnt(0)" ::: "memory");
    __builtin_amdgcn_sched_barrier(0);
    __builtin_amdgcn_s_setprio(1);
#pragma unroll
    for (int m = 0; m < 4; ++m)
#pragma unroll
      for (int n = 0; n < 4; ++n)
        acc[m][n] = mfma_fp4(av[m], b0[n], acc[m][n]);
    __builtin_amdgcn_s_setprio(0);
    __builtin_amdgcn_s_barrier();

    // ===== phase 2: read A(mh0,k1)+B(*,k1) ; stage A1(t+1) ; MFMA mh0 x k1 =====
#pragma unroll
    for (int m = 0; m < 4; ++m) {
      int row = m * 16 + l15;
      int col = (64 + g4 * 16) ^ ((row & 7) << 4);
      av[m] = *(const i32x4*)&As[row * 128 + col];
    }
#pragma unroll
    for (int n = 0; n < 4; ++n) {
      int row = brow0 + n * 16 + l15;
      int col = (64 + g4 * 16) ^ ((row & 7) << 4);
      b1[n] = *(const i32x4*)&Bs[row * 128 + col];
    }
    if (t + 1 < NT) stage(buf ^ 1, 1, Anext + (size_t)128 * KB);
    __builtin_amdgcn_s_barrier();
    asm volatile("s_waitcnt lgkmcnt(0)" ::: "memory");
    __builtin_amdgcn_sched_barrier(0);
    __builtin_amdgcn_s_setprio(1);
#pragma unroll
    for (int m = 0; m < 4; ++m)
#pragma unroll
      for (int n = 0; n < 4; ++n)
        acc[m][n] = mfma_fp4(av[m], b1[n], acc[m][n]);
    __builtin_amdgcn_s_setprio(0);
    __builtin_amdgcn_s_barrier();

    // ===== phase 3: read A(mh1,k0) ; stage B0(t+2) ; MFMA mh1 x k0 (reuse b0) =====
#pragma unroll
    for (int m = 0; m < 4; ++m) {
      int row = 64 + m * 16 + l15;
      int col = (g4 * 16) ^ ((row & 7) << 4);
      av[m] = *(const i32x4*)&As[row * 128 + col];
    }
    if (t + 2 < NT) stage(buf, 2, Bnext2);
    __builtin_amdgcn_s_barrier();
    asm volatile("s_waitcnt lgkmcnt(0)" ::: "memory");
    __builtin_amdgcn_sched_barrier(0);
    __builtin_amdgcn_s_setprio(1);
#pragma unroll
    for (int m = 0; m < 4; ++m)
#pragma unroll
      for (int n = 0; n < 4; ++n)
        acc[4 + m][n] = mfma_fp4(av[m], b0[n], acc[4 + m][n]);
    __builtin_amdgcn_s_setprio(0);
    __builtin_amdgcn_s_barrier();

    // ===== phase 4: read A(mh1,k1) ; stage B1(t+2) ; MFMA mh1 x k1 (reuse b1) =====
#pragma unroll
    for (int m = 0; m < 4; ++m) {
      int row = 64 + m * 16 + l15;
      int col = (64 + g4 * 16) ^ ((row & 7) << 4);
      av[m] = *(const i32x4*)&As[row * 128 + col];
    }
    if (t + 2 < NT) stage(buf, 3, Bnext2 + (size_t)128 * KB);
    __builtin_amdgcn_s_barrier();
    asm volatile("s_waitcnt lgkmcnt(0)" ::: "memory");
    __builtin_amdgcn_sched_barrier(0);
    __builtin_amdgcn_s_setprio(1);
#pragma unroll
    for (int m = 0; m < 4; ++m)
#pragma unroll
      for (int n = 0; n < 4; ++n)
        acc[4 + m][n] = mfma_fp4(av[m], b1[n], acc[4 + m][n]);
    __builtin_amdgcn_s_setprio(0);
    // drain tile t+1's half-tiles; keep B(t+2) (4 loads) in flight
    if (t + 2 < NT)
      asm volatile("s_waitcnt vmcnt(4)" ::: "memory");
    else
      asm volatile("s_waitcnt vmcnt(0)" ::: "memory");
    __builtin_amdgcn_s_barrier();
  }

  // ---- epilogue: C/D layout col = lane&15, row = (lane>>4)*4 + reg ----
  const int crow0 = bm + wr * 128;
  const int ccol0 = bn + wc * 64;
#pragma unroll
  for (int m = 0; m < 8; ++m)
#pragma unroll
    for (int n = 0; n < 4; ++n)
#pragma unroll
      for (int j = 0; j < 4; ++j)
        C[(size_t)(crow0 + m * 16 + g4 * 4 + j) * N_DIM + ccol0 + n * 16 + l15] = acc[m][n][j];
}

// -------- naive fallback (only if workspace is too small) --------
__global__ void naive_bin_gemm(const float* __restrict__ X, const float* __restrict__ W,
                               float* __restrict__ C) {
  int j = blockIdx.x * blockDim.x + threadIdx.x;
  int i = blockIdx.y;
  if (j >= N_DIM) return;
  float s = 0.0f;
  for (int k = 0; k < K_DIM; ++k) {
    float xv = X[(size_t)i * K_DIM + k];
    float wv = W[(size_t)k * N_DIM + j];
    float sx = (float)((xv > 0.0f) - (xv < 0.0f));
    float sw = (float)((wv > 0.0f) - (wv < 0.0f));
    s += sx * sw;
  }
  C[(size_t)i * N_DIM + j] = s;
}

extern "C" void kernel_launch(void* const* d_in, const int* in_sizes, int n_in,
                              void* d_out, int out_size, void* d_ws, size_t ws_size,
                              hipStream_t stream) {
  const float* x = (const float*)d_in[0];  // [M][K]
  const float* w = (const float*)d_in[1];  // [K][N]
  float* out = (float*)d_out;              // [M][N]

  const size_t xb_bytes = (size_t)M_DIM * KB;  // 16.8 MB
  const size_t wt_bytes = (size_t)N_DIM * KB;  // 8.4 MB

  if (ws_size >= xb_bytes + wt_bytes) {
    u8* xb = (u8*)d_ws;
    u8* wt = (u8*)((char*)d_ws + xb_bytes);

    binarize_fused<<<4096 + 2048, 256, 0, stream>>>(x, w, (u32*)xb, wt);

    const int grid = (M_DIM / BM) * (N_DIM / BN);  // 32 * 16 = 512
    gemm_bin_fp4<<<grid, 512, 0, stream>>>(xb, wt, out);
  } else {
    naive_bin_gemm<<<dim3(N_DIM / 256, M_DIM), dim3(256), 0, stream>>>(x, w, out);
  }
}

// Round 8
// 125.761 us; speedup vs baseline: 1.0623x; 1.0129x over previous
//
#include <hip/hip_runtime.h>
#include <stdint.h>

#define M_DIM 8192
#define K_DIM 4096
#define N_DIM 4096
#define KB (K_DIM / 2)  // bytes per packed-fp4 row: 2048

typedef unsigned char u8;
typedef unsigned int u32;
typedef int i32x4 __attribute__((ext_vector_type(4)));
typedef int i32x8 __attribute__((ext_vector_type(8)));
typedef float f32x4 __attribute__((ext_vector_type(4)));
typedef float float4v __attribute__((ext_vector_type(4)));
typedef u32 u32x2 __attribute__((ext_vector_type(2)));

// sign(v) as fp4 e2m1 code: +1 -> 0x2, -1 -> 0xA, 0 -> 0x0
__device__ __forceinline__ u32 sign_fp4(float v) {
  return v > 0.0f ? 0x2u : (v < 0.0f ? 0xAu : 0x0u);
}

// pack 4 byte-codes (one per byte of v) into 4 nibbles (16-bit result)
__device__ __forceinline__ u32 pk16(u32 v) {
  return (v & 0xFu) | ((v >> 4) & 0xF0u) | ((v >> 8) & 0xF00u) | ((v >> 12) & 0xF000u);
}

// ---------------- fused preprocessing -----------------------------
// 6144 blocks, interleaved: bid%3==2 -> X binarize chunk (2048 chunks),
// else -> W transpose tile (4096 tiles). Interleaving keeps both parts
// resident on the GPU concurrently instead of W-then-X serialization.
__global__ void binarize_fused(const float* __restrict__ x, const float* __restrict__ w,
                               u32* __restrict__ xb, u8* __restrict__ wT) {
  const int tid = threadIdx.x;
  const int bid = blockIdx.x;
  const int r3 = bid % 3;
  if (r3 != 2) {
    // ---- W transpose part: one 64x64 tile per block ----
    __shared__ u8 tile[64][68];  // 68-B rows: 4-aligned, odd dword stride
    const int wtile = (bid / 3) * 2 + r3;  // 0..4095 bijective
    const int bn = (wtile & 63) * 64;
    const int bk = (wtile >> 6) * 64;

#pragma unroll
    for (int it = 0; it < 4; ++it) {
      int idx = tid + it * 256;
      int rr = idx >> 4;       // k-local
      int c = (idx & 15) * 4;  // n-local
      float4v v = *(const float4v*)&w[(size_t)(bk + rr) * N_DIM + bn + c];
      tile[c + 0][rr] = (u8)sign_fp4(v.x);
      tile[c + 1][rr] = (u8)sign_fp4(v.y);
      tile[c + 2][rr] = (u8)sign_fp4(v.z);
      tile[c + 3][rr] = (u8)sign_fp4(v.w);
    }
    __syncthreads();
    // pack: each thread emits 8 output bytes (16 k-codes) of one n-row
    const int rn = tid >> 2;          // n-local 0..63
    const int cbyte = (tid & 3) * 8;  // output byte offset 0..24
    const u32* trow = (const u32*)&tile[rn][0];
    u32 q0 = trow[cbyte / 2 + 0];
    u32 q1 = trow[cbyte / 2 + 1];
    u32 q2 = trow[cbyte / 2 + 2];
    u32 q3 = trow[cbyte / 2 + 3];
    u32x2 o;
    o.x = pk16(q0) | (pk16(q1) << 16);
    o.y = pk16(q2) | (pk16(q3) << 16);
    *(u32x2*)&wT[(size_t)(bn + rn) * KB + (bk >> 1) + cbyte] = o;
  } else {
    // ---- X binarize part ----
    const int n8 = M_DIM * K_DIM / 8;
    int i = (bid / 3) * 256 + tid;
    const int stride = 2048 * 256;
    for (; i < n8; i += stride) {
      float4v v0 = ((const float4v*)x)[2 * i];
      float4v v1 = ((const float4v*)x)[2 * i + 1];
      u32 wd = sign_fp4(v0.x) | (sign_fp4(v0.y) << 4) | (sign_fp4(v0.z) << 8) |
               (sign_fp4(v0.w) << 12) | (sign_fp4(v1.x) << 16) | (sign_fp4(v1.y) << 20) |
               (sign_fp4(v1.z) << 24) | (sign_fp4(v1.w) << 28);
      xb[i] = wd;
    }
  }
}

// ------------------------------------------------------------------
// 2-barrier 256x256 fp4 GEMM: C[M][N] = A[M][K] * Bt[N][K]^T, fp4 in, f32 out.
// mfma_scale_f32_16x16x128_f8f6f4 (scale=1.0). K-tile = 256 elems = 128-B rows.
// All 24 ds_reads issued in 3 early batches; MFMA clusters overlap later
// batches' LDS completion via the compiler's counted lgkm waits. Only 2
// barriers/iter: mid (before B(t+2) stage, WAR) and end (staged-data RAW,
// with counted vmcnt(4)). T2 byte-XOR swizzle via pre-swizzled global source.
// ------------------------------------------------------------------
#define BM 256
#define BN 256
#define BKB 128           // bytes of K per tile (= 256 fp4 elems)
#define NT (K_DIM / 256)  // 16

__device__ __forceinline__ void gload_lds16(const u8* g, u8* l) {
  __builtin_amdgcn_global_load_lds(
      (const __attribute__((address_space(1))) void*)g,
      (__attribute__((address_space(3))) void*)l, 16, 0, 0);
}

// undef hi half: fp4 f8f6f4 MFMA ignores regs [4:7] of each operand
__device__ __forceinline__ i32x8 pad8(i32x4 v) {
  return __builtin_shufflevector(v, v, 0, 1, 2, 3, -1, -1, -1, -1);
}

// fp4 x fp4, per-lane e8m0 scale byte 0x7F (=1.0), opsel byte 0
__device__ __forceinline__ f32x4 mfma_fp4(i32x4 a, i32x4 b, f32x4 c) {
  return __builtin_amdgcn_mfma_scale_f32_16x16x128_f8f6f4(pad8(a), pad8(b), c, 4, 4, 0, 0x7F, 0,
                                                          0x7F);
}

__global__ __launch_bounds__(512, 2) void gemm_bin_fp4(const u8* __restrict__ A,
                                                       const u8* __restrict__ Bt,
                                                       float* __restrict__ C) {
  // slots: 0 = A rows[0,128), 1 = A rows[128,256), 2 = Bt[0,128), 3 = Bt[128,256)
  __shared__ u8 lds[2][4][128 * 128];

  const int tid = threadIdx.x;
  const int lane = tid & 63;
  const int wid = tid >> 6;  // 0..7
  const int wr = wid >> 2;   // 0..1 (M half)
  const int wc = wid & 3;    // 0..3 (N quarter)

  // XCD-aware swizzle, nwg = 512 (divisible by 8 -> bijective)
  const int b = blockIdx.x;
  const int sw = (b & 7) * (gridDim.x >> 3) + (b >> 3);
  const int tiles_n = N_DIM / BN;  // 16
  const int bm = (sw / tiles_n) * BM;
  const int bn = (sw % tiles_n) * BN;

  const int l15 = lane & 15;
  const int g4 = lane >> 4;
  const int srow = lane >> 3;                      // 0..7
  const int swz_src = (((lane & 7) ^ srow) << 4);  // pre-swizzled byte col

  // stage one 128-row x 128-B half-tile (2 x global_load_lds per wave).
  auto stage = [&](int buf, int slot, const u8* gbase) {
#pragma unroll
    for (int i = 0; i < 2; ++i) {
      const u8* g = gbase + (size_t)(i * 64 + wid * 8 + srow) * KB + swz_src;
      gload_lds16(g, &lds[buf][slot][(i * 64 + wid * 8) * 128]);
    }
  };

  f32x4 acc[8][4] = {};

  // ---- prologue: tile0 fully + B half of tile1 (12 loads) ----
  {
    const u8* Abase = A + (size_t)bm * KB;
    const u8* Bbase = Bt + (size_t)bn * KB;
    stage(0, 0, Abase);
    stage(0, 1, Abase + (size_t)128 * KB);
    stage(0, 2, Bbase);
    stage(0, 3, Bbase + (size_t)128 * KB);
    stage(1, 2, Bbase + BKB);
    stage(1, 3, Bbase + (size_t)128 * KB + BKB);
  }
  asm volatile("s_waitcnt vmcnt(4)" ::: "memory");  // tile0 ready, B(1) in flight
  __builtin_amdgcn_s_barrier();

  for (int t = 0; t < NT; ++t) {
    const int buf = t & 1;
    const u8* As = &lds[buf][wr][0];
    const u8* Bs = &lds[buf][2 + (wc >> 1)][0];
    const int brow0 = (wc & 1) * 64;
    const u8* Anext = A + (size_t)bm * KB + (t + 1) * BKB;    // tile t+1
    const u8* Bnext2 = Bt + (size_t)bn * KB + (t + 2) * BKB;  // tile t+2

    i32x4 a0[4], a1[4], a2[4], a3[4], b0[4], b1[4];

    // ===== R1: A(mh0,k0) + B(*,k0); stage A(t+1) into buf^1 =====
#pragma unroll
    for (int m = 0; m < 4; ++m) {
      int row = m * 16 + l15;
      int col = (g4 * 16) ^ ((row & 7) << 4);
      a0[m] = *(const i32x4*)&As[row * 128 + col];
    }
#pragma unroll
    for (int n = 0; n < 4; ++n) {
      int row = brow0 + n * 16 + l15;
      int col = (g4 * 16) ^ ((row & 7) << 4);
      b0[n] = *(const i32x4*)&Bs[row * 128 + col];
    }
    if (t + 1 < NT) {
      stage(buf ^ 1, 0, Anext);
      stage(buf ^ 1, 1, Anext + (size_t)128 * KB);
    }
    __builtin_amdgcn_sched_barrier(0);

    // ===== R2: A(mh0,k1) + B(*,k1) =====
#pragma unroll
    for (int m = 0; m < 4; ++m) {
      int row = m * 16 + l15;
      int col = (64 + g4 * 16) ^ ((row & 7) << 4);
      a1[m] = *(const i32x4*)&As[row * 128 + col];
    }
#pragma unroll
    for (int n = 0; n < 4; ++n) {
      int row = brow0 + n * 16 + l15;
      int col = (64 + g4 * 16) ^ ((row & 7) << 4);
      b1[n] = *(const i32x4*)&Bs[row * 128 + col];
    }
    __builtin_amdgcn_sched_barrier(0);

    // ===== cluster 1: mh0 x k0 (compiler waits only for R1) =====
    __builtin_amdgcn_s_setprio(1);
#pragma unroll
    for (int m = 0; m < 4; ++m)
#pragma unroll
      for (int n = 0; n < 4; ++n)
        acc[m][n] = mfma_fp4(a0[m], b0[n], acc[m][n]);
    __builtin_amdgcn_s_setprio(0);
    __builtin_amdgcn_sched_barrier(0);

    // ===== R3+R4: A(mh1,k0), A(mh1,k1) — overlap cluster 2 =====
#pragma unroll
    for (int m = 0; m < 4; ++m) {
      int row = 64 + m * 16 + l15;
      int col = (g4 * 16) ^ ((row & 7) << 4);
      a2[m] = *(const i32x4*)&As[row * 128 + col];
    }
#pragma unroll
    for (int m = 0; m < 4; ++m) {
      int row = 64 + m * 16 + l15;
      int col = (64 + g4 * 16) ^ ((row & 7) << 4);
      a3[m] = *(const i32x4*)&As[row * 128 + col];
    }
    __builtin_amdgcn_sched_barrier(0);

    // ===== cluster 2: mh0 x k1 (waits R2; R3/R4 stay in flight) =====
    __builtin_amdgcn_s_setprio(1);
#pragma unroll
    for (int m = 0; m < 4; ++m)
#pragma unroll
      for (int n = 0; n < 4; ++n)
        acc[m][n] = mfma_fp4(a1[m], b1[n], acc[m][n]);
    __builtin_amdgcn_s_setprio(0);

    // all waves' B reads complete here (each passed its cluster-2 operand wait)
    __builtin_amdgcn_s_barrier();

    // ===== stage B(t+2) into buf slots 2-3 (WAR now safe) =====
    if (t + 2 < NT) {
      stage(buf, 2, Bnext2);
      stage(buf, 3, Bnext2 + (size_t)128 * KB);
    }
    __builtin_amdgcn_sched_barrier(0);

    // ===== cluster 3: mh1 x k0 (waits R3) =====
    __builtin_amdgcn_s_setprio(1);
#pragma unroll
    for (int m = 0; m < 4; ++m)
#pragma unroll
      for (int n = 0; n < 4; ++n)
        acc[4 + m][n] = mfma_fp4(a2[m], b0[n], acc[4 + m][n]);
    __builtin_amdgcn_s_setprio(0);
    __builtin_amdgcn_sched_barrier(0);

    // ===== cluster 4: mh1 x k1 (waits R4) =====
    __builtin_amdgcn_s_setprio(1);
#pragma unroll
    for (int m = 0; m < 4; ++m)
#pragma unroll
      for (int n = 0; n < 4; ++n)
        acc[4 + m][n] = mfma_fp4(a3[m], b1[n], acc[4 + m][n]);
    __builtin_amdgcn_s_setprio(0);

    // drain staged A(t+1) (+ B(t+1) from t-1); keep B(t+2) in flight
    if (t + 2 < NT)
      asm volatile("s_waitcnt vmcnt(4)" ::: "memory");
    else
      asm volatile("s_waitcnt vmcnt(0)" ::: "memory");
    __builtin_amdgcn_s_barrier();
  }

  // ---- epilogue: C/D layout col = lane&15, row = (lane>>4)*4 + reg ----
  const int crow0 = bm + wr * 128;
  const int ccol0 = bn + wc * 64;
#pragma unroll
  for (int m = 0; m < 8; ++m)
#pragma unroll
    for (int n = 0; n < 4; ++n)
#pragma unroll
      for (int j = 0; j < 4; ++j)
        C[(size_t)(crow0 + m * 16 + g4 * 4 + j) * N_DIM + ccol0 + n * 16 + l15] = acc[m][n][j];
}

// -------- naive fallback (only if workspace is too small) --------
__global__ void naive_bin_gemm(const float* __restrict__ X, const float* __restrict__ W,
                               float* __restrict__ C) {
  int j = blockIdx.x * blockDim.x + threadIdx.x;
  int i = blockIdx.y;
  if (j >= N_DIM) return;
  float s = 0.0f;
  for (int k = 0; k < K_DIM; ++k) {
    float xv = X[(size_t)i * K_DIM + k];
    float wv = W[(size_t)k * N_DIM + j];
    float sx = (float)((xv > 0.0f) - (xv < 0.0f));
    float sw = (float)((wv > 0.0f) - (wv < 0.0f));
    s += sx * sw;
  }
  C[(size_t)i * N_DIM + j] = s;
}

extern "C" void kernel_launch(void* const* d_in, const int* in_sizes, int n_in,
                              void* d_out, int out_size, void* d_ws, size_t ws_size,
                              hipStream_t stream) {
  const float* x = (const float*)d_in[0];  // [M][K]
  const float* w = (const float*)d_in[1];  // [K][N]
  float* out = (float*)d_out;              // [M][N]

  const size_t xb_bytes = (size_t)M_DIM * KB;  // 16.8 MB
  const size_t wt_bytes = (size_t)N_DIM * KB;  // 8.4 MB

  if (ws_size >= xb_bytes + wt_bytes) {
    u8* xb = (u8*)d_ws;
    u8* wt = (u8*)((char*)d_ws + xb_bytes);

    binarize_fused<<<6144, 256, 0, stream>>>(x, w, (u32*)xb, wt);

    const int grid = (M_DIM / BM) * (N_DIM / BN);  // 32 * 16 = 512
    gemm_bin_fp4<<<grid, 512, 0, stream>>>(xb, wt, out);
  } else {
    naive_bin_gemm<<<dim3(N_DIM / 256, M_DIM), dim3(256), 0, stream>>>(x, w, out);
  }
}